// Round 4
// baseline (316.110 us; speedup 1.0000x reference)
//
#include <hip/hip_runtime.h>

// out[s,:] = mask[s] ? source[C(s),:] : inputs[s,:], C(s) = #masked rows < s.
// prep resolves per-row pointers; gather is a max-MLP float4 streaming copy.

typedef float f4 __attribute__((ext_vector_type(4)));

#define S_ROWS 8192
#define D4 1024                       // float4 per row (D=4096)
#define PREP_THREADS 256
#define ROWS_PER_THREAD (S_ROWS / PREP_THREADS)  // 32
#define GATHER_BLOCKS 2048
#define GATHER_THREADS 256
#define STRIDE (GATHER_BLOCKS * GATHER_THREADS)  // 524288
#define TOTAL_F4 (S_ROWS * D4)                   // 8388608
#define ITERS (TOTAL_F4 / STRIDE)                // 16

// Single-block: detect mask layout, prefix-count masked rows, emit row pointers.
__global__ __launch_bounds__(PREP_THREADS) void prep_kernel(
    const void* __restrict__ mask_raw, const f4* __restrict__ in,
    const f4* __restrict__ src, const f4** __restrict__ rowptr) {
  __shared__ int s_not01, s_notF;
  __shared__ int sums[PREP_THREADS];
  __shared__ int excl[PREP_THREADS];
  const int t = threadIdx.x;
  if (t == 0) { s_not01 = 0; s_notF = 0; }
  __syncthreads();

  // Layout detection over first S_ROWS bytes (valid in every layout):
  //   int32 -> words all 0/1; float32 -> words all 0/0x3F800000; else bytes.
  const unsigned int* w = (const unsigned int*)mask_raw;
  int not01 = 0, notF = 0;
  for (int i = t; i < S_ROWS / 4; i += PREP_THREADS) {
    const unsigned int v = w[i];
    not01 |= (v > 1u) ? 1 : 0;
    notF  |= (v != 0u && v != 0x3F800000u) ? 1 : 0;
  }
  if (not01) atomicOr(&s_not01, 1);
  if (notF)  atomicOr(&s_notF, 1);
  __syncthreads();
  const int mode = (!s_not01) ? 0 : ((!s_notF) ? 1 : 2);  // 0=i32, 1=f32, 2=u8

  int vals[ROWS_PER_THREAD];
  const int base = t * ROWS_PER_THREAD;
  int local = 0;
  for (int k = 0; k < ROWS_PER_THREAD; ++k) {
    const int s = base + k;
    int mv;
    if (mode == 0)      mv = (((const int*)mask_raw)[s] != 0);
    else if (mode == 1) mv = (((const float*)mask_raw)[s] != 0.0f);
    else                mv = (((const unsigned char*)mask_raw)[s] != 0);
    vals[k] = mv;
    local += mv;
  }
  sums[t] = local;
  __syncthreads();
  if (t == 0) {  // serial 256-entry exclusive scan — trivial
    int acc = 0;
    for (int i = 0; i < PREP_THREADS; ++i) { excl[i] = acc; acc += sums[i]; }
  }
  __syncthreads();
  int run = excl[t];
  for (int k = 0; k < ROWS_PER_THREAD; ++k) {
    const int s = base + k;
    rowptr[s] = vals[k] ? (src + (size_t)run * D4) : (in + (size_t)s * D4);
    run += vals[k];
  }
}

// Flat streaming gather-copy: 16 independent float4 chains per thread,
// wave-contiguous 1 KiB per access, nontemporal stores for the write stream.
__global__ __launch_bounds__(GATHER_THREADS) void gather_kernel(
    const f4* const* __restrict__ rowptr, f4* __restrict__ out) {
  const int idx = blockIdx.x * GATHER_THREADS + threadIdx.x;
#pragma unroll
  for (int k = 0; k < ITERS; ++k) {
    const int i = idx + k * STRIDE;
    const f4* __restrict__ p = rowptr[i >> 10];   // wave-uniform, L2-hot 64 KiB
    const f4 v = p[i & 1023];
    __builtin_nontemporal_store(v, out + i);
  }
}

extern "C" void kernel_launch(void* const* d_in, const int* in_sizes, int n_in,
                              void* d_out, int out_size, void* d_ws, size_t ws_size,
                              hipStream_t stream) {
  const f4* inputs = (const f4*)d_in[0];
  const void* mask = d_in[1];
  const f4* source = (const f4*)d_in[2];
  f4* out = (f4*)d_out;
  const f4** rowptr = (const f4**)d_ws;  // 8192 * 8 B = 64 KiB scratch

  prep_kernel<<<1, PREP_THREADS, 0, stream>>>(mask, inputs, source, rowptr);
  gather_kernel<<<GATHER_BLOCKS, GATHER_THREADS, 0, stream>>>(rowptr, out);
}

// Round 5
// 298.912 us; speedup vs baseline: 1.0575x; 1.0575x over previous
//
#include <hip/hip_runtime.h>

// out[s,:] = mask[s] ? source[C(s),:] : inputs[s,:], C(s) = #masked rows < s.
// prep: row-level mask decode + prefix count -> rowsrc[s] (C(s) or -1).
// gather: 2 rows per block, 8 independent float4 loads per thread (load
// phase fully issued before store phase) for deep memory-level parallelism.

typedef float f4 __attribute__((ext_vector_type(4)));

#define S_ROWS 8192
#define D4 1024                        // float4 per row (D=4096)
#define PREP_THREADS 256
#define ROWS_PER_THREAD (S_ROWS / PREP_THREADS)  // 32
#define ROWS_PER_BLOCK 2
#define GATHER_BLOCKS (S_ROWS / ROWS_PER_BLOCK)  // 4096
#define GATHER_THREADS 256
#define F4_PER_THREAD (D4 / GATHER_THREADS)      // 4 per row

// Single-block: detect mask storage layout, prefix-count masked rows,
// emit rowsrc[s] = C(s) if masked else -1.
__global__ __launch_bounds__(PREP_THREADS) void prep_kernel(
    const void* __restrict__ mask_raw, int* __restrict__ rowsrc) {
  __shared__ int s_not01, s_notF;
  __shared__ int sums[PREP_THREADS];
  __shared__ int excl[PREP_THREADS];
  const int t = threadIdx.x;
  if (t == 0) { s_not01 = 0; s_notF = 0; }
  __syncthreads();

  // Layout detection over first S_ROWS bytes (valid in every layout):
  //   int32 -> words all 0/1; float32 -> words all 0/0x3F800000; else bytes.
  const unsigned int* w = (const unsigned int*)mask_raw;
  int not01 = 0, notF = 0;
  for (int i = t; i < S_ROWS / 4; i += PREP_THREADS) {
    const unsigned int v = w[i];
    not01 |= (v > 1u) ? 1 : 0;
    notF  |= (v != 0u && v != 0x3F800000u) ? 1 : 0;
  }
  if (not01) atomicOr(&s_not01, 1);
  if (notF)  atomicOr(&s_notF, 1);
  __syncthreads();
  const int mode = (!s_not01) ? 0 : ((!s_notF) ? 1 : 2);  // 0=i32, 1=f32, 2=u8

  int vals[ROWS_PER_THREAD];
  const int base = t * ROWS_PER_THREAD;
  int local = 0;
  for (int k = 0; k < ROWS_PER_THREAD; ++k) {
    const int s = base + k;
    int mv;
    if (mode == 0)      mv = (((const int*)mask_raw)[s] != 0);
    else if (mode == 1) mv = (((const float*)mask_raw)[s] != 0.0f);
    else                mv = (((const unsigned char*)mask_raw)[s] != 0);
    vals[k] = mv;
    local += mv;
  }
  sums[t] = local;
  __syncthreads();
  if (t == 0) {  // serial 256-entry exclusive scan — trivial
    int acc = 0;
    for (int i = 0; i < PREP_THREADS; ++i) { excl[i] = acc; acc += sums[i]; }
  }
  __syncthreads();
  int run = excl[t];
  for (int k = 0; k < ROWS_PER_THREAD; ++k) {
    const int s = base + k;
    rowsrc[s] = vals[k] ? run : -1;
    run += vals[k];
  }
}

// 2 rows per block; per thread: 8 independent float4 loads (all issued
// before any store), then 8 coalesced stores. Row source resolved once.
__global__ __launch_bounds__(GATHER_THREADS) void gather_kernel(
    const f4* __restrict__ in, const f4* __restrict__ src,
    const int* __restrict__ rowsrc, f4* __restrict__ out) {
  const int s0 = blockIdx.x * ROWS_PER_BLOCK;
  const int t = threadIdx.x;
  const int r0 = rowsrc[s0];
  const int r1 = rowsrc[s0 + 1];
  const f4* __restrict__ p0 =
      (r0 >= 0) ? (src + (size_t)r0 * D4) : (in + (size_t)s0 * D4);
  const f4* __restrict__ p1 =
      (r1 >= 0) ? (src + (size_t)r1 * D4) : (in + (size_t)(s0 + 1) * D4);
  f4* __restrict__ o0 = out + (size_t)s0 * D4;
  f4* __restrict__ o1 = o0 + D4;

  f4 v[2 * F4_PER_THREAD];
#pragma unroll
  for (int k = 0; k < F4_PER_THREAD; ++k) v[k] = p0[t + k * GATHER_THREADS];
#pragma unroll
  for (int k = 0; k < F4_PER_THREAD; ++k)
    v[F4_PER_THREAD + k] = p1[t + k * GATHER_THREADS];
#pragma unroll
  for (int k = 0; k < F4_PER_THREAD; ++k) o0[t + k * GATHER_THREADS] = v[k];
#pragma unroll
  for (int k = 0; k < F4_PER_THREAD; ++k)
    o1[t + k * GATHER_THREADS] = v[F4_PER_THREAD + k];
}

extern "C" void kernel_launch(void* const* d_in, const int* in_sizes, int n_in,
                              void* d_out, int out_size, void* d_ws, size_t ws_size,
                              hipStream_t stream) {
  const f4* inputs = (const f4*)d_in[0];
  const void* mask = d_in[1];
  const f4* source = (const f4*)d_in[2];
  f4* out = (f4*)d_out;
  int* rowsrc = (int*)d_ws;  // 8192 ints = 32 KiB scratch

  prep_kernel<<<1, PREP_THREADS, 0, stream>>>(mask, rowsrc);
  gather_kernel<<<GATHER_BLOCKS, GATHER_THREADS, 0, stream>>>(
      inputs, source, rowsrc, out);
}